// Round 16
// baseline (211.834 us; speedup 1.0000x reference)
//
#include <hip/hip_runtime.h>
#include <hip/hip_cooperative_groups.h>

namespace cg = cooperative_groups;

#define B_ 4
#define N_ 4096
#define C_ 256
#define M_ 2048

typedef __attribute__((ext_vector_type(8))) short short8;
typedef __attribute__((ext_vector_type(4))) float f32x4;

union U16x8 { uint4 u4; unsigned short us[8]; short8 s8; };
union U16x4 { uint2 u2; unsigned short us[4]; };

__device__ __forceinline__ float bf2f(unsigned short h) {
    unsigned int u = ((unsigned int)h) << 16;
    return __builtin_bit_cast(float, u);
}
__device__ __forceinline__ unsigned short f2bf(float f) {
    unsigned int u = __builtin_bit_cast(unsigned int, f);
    u += 0x7FFFu + ((u >> 16) & 1u);
    return (unsigned short)(u >> 16);
}

#define GLB_AS(p) ((const __attribute__((address_space(1))) unsigned int*)(p))
#define LDS_AS(p) ((__attribute__((address_space(3))) unsigned int*)(p))

// ---------------- Fused cooperative kernel (v20) ----------------
// ONE kernel: prep phase (norms + casts into gmc [m][c] and gcm3 pair-frag)
// -> threadfence + grid.sync -> v19b main body VERBATIM.
// Motivation: across 9 passing rounds, total - k_main = 58-70us regardless of
// prepass structure; k_prep never visible in top-5. Fusion removes the launch
// boundary AND measures prep's true cost (fused dur - 68.5).
// Grid 256 x 512 = exactly 1 block/CU at the 256-reg footprint (co-resident).
//
// Prep distribution: bid -> unit=(bid>>1) in [0,128) = (m-tile t, batch b);
// ch=bid&1 selects c-half {ch*128, ch*128+64}. Phase-1 norms duplicated
// across the (even,odd) block pair (16KB read, negligible).
//
// gcm3 layout (pair-interleaved fragment-linear, v19b-verified):
//   short-off = pair*32768 + kh*8192 + ct*512 + kq*128 + cr*8 + parity*4 + r
//   = graw[c=ct*16+cr][key=(2*pair+parity)*64 + kh*16 + kq*4 + r]
__global__ __launch_bounds__(512, 1) void k_fused(
    const float* __restrict__ l,
    const float* __restrict__ g,
    unsigned short* __restrict__ gcm3,   // ws: pair-frag raw (GEMM2 B), 4 MB
    unsigned short* __restrict__ gmc,    // ws: [B][M][C] normalized (GEMM1 A), 4 MB
    float* __restrict__ out)
{
    __shared__ __align__(16) char sMem[132096];

    const int tid = threadIdx.x;
    const int bid = blockIdx.x;

    // ================= PHASE A: prep =================
    {
        float (*red)[64] = (float (*)[64])sMem;                 // 2 KB
        float* sInv = (float*)(sMem + 2048);                    // 256 B
        unsigned short* T = (unsigned short*)(sMem + 2304);     // 64*66*2 = 8448 B

        const int unit = bid >> 1;           // 0..127
        const int t = unit & 31;             // m-tile
        const int b = unit >> 5;             // batch
        const int ch = bid & 1;              // c-half
        const int m0 = t * 64;
        const int ml = tid & 63, cq = tid >> 6;   // cq in [0,8)

        // phase 1: norms (duplicated across the block pair)
        const float* gb = g + (size_t)b * C_ * M_ + m0 + ml;
        float ss = 0.f;
#pragma unroll 4
        for (int i = 0; i < 32; ++i) {
            float v = gb[(size_t)(cq * 32 + i) * M_];
            ss += v * v;
        }
        red[cq][ml] = ss;
        __syncthreads();
        if (cq == 0) {
            float t0 = 0.f;
#pragma unroll
            for (int k = 0; k < 8; ++k) t0 += red[k][ml];
            sInv[ml] = 1.f / fmaxf(sqrtf(t0), 1e-8f);
        }
        __syncthreads();

        unsigned short* gmcb = gmc + ((size_t)b * M_ + m0) * C_;
        unsigned short* gcm3b = gcm3 + (size_t)b * 524288 +
                                (size_t)(t >> 1) * 32768 + (t & 1) * 4;

        // phase 2: this block's 2 c-tiles of 64
        for (int c0 = ch * 128; c0 < ch * 128 + 128; c0 += 64) {
            const float* gbase = g + ((size_t)b * C_ + c0) * M_ + m0;
#pragma unroll
            for (int j = 0; j < 2; ++j) {
                int id = tid + 512 * j;                 // 1024 float4-chunks
                int ci = id >> 4, mq = (id & 15) * 4;   // ci: c in tile; mq: key
                float4 v = *(const float4*)(gbase + (size_t)ci * M_ + mq);
                uint2 pk;
                pk.x = (unsigned)f2bf(v.x) | ((unsigned)f2bf(v.y) << 16);
                pk.y = (unsigned)f2bf(v.z) | ((unsigned)f2bf(v.w) << 16);
                const int cg = c0 + ci;
                const int kh = mq >> 4, kq = (mq >> 2) & 3;
                *(uint2*)(gcm3b + kh * 8192 + (cg >> 4) * 512 + kq * 128 +
                          (cg & 15) * 8) = pk;
                T[ci * 66 + mq + 0] = f2bf(v.x * sInv[mq + 0]);
                T[ci * 66 + mq + 1] = f2bf(v.y * sInv[mq + 1]);
                T[ci * 66 + mq + 2] = f2bf(v.z * sInv[mq + 2]);
                T[ci * 66 + mq + 3] = f2bf(v.w * sInv[mq + 3]);
            }
            __syncthreads();
            {                                           // 512 8-short chunks
                int mr = tid >> 3, cc8 = (tid & 7) * 8;
                U16x8 t8;
#pragma unroll
                for (int k = 0; k < 8; ++k) t8.us[k] = T[(cc8 + k) * 66 + mr];
                *(uint4*)(gmcb + (size_t)mr * C_ + c0 + cc8) = t8.u4;
            }
            __syncthreads();   // T reused next tile
        }
    }

    __threadfence();           // prep writes visible device-wide
    cg::this_grid().sync();    // all blocks' prep done

    // ================= PHASE B: main (v19b verbatim) =================
    unsigned short* sGmcD = (unsigned short*)sMem;             // ghat [2][64][256], 64 KB
    unsigned short* sGcm3 = (unsigned short*)(sMem + 65536);   // V pair-frag, 64 KB
    float (*sDen)[64] = (float (*)[64])(sMem + 131072);        // [4 kh][64 rows]

    const int w = tid >> 6;
    const int lane = tid & 63;
    const int l15 = lane & 15;
    const int quad = lane >> 4;
    const int kh = w & 3;        // key-quarter
    const int rh = w >> 2;       // row-half

    // batch-clustered XCD swizzle (bijective over 256 blocks)
    const int xcd = bid & 7;
    const int b = xcd >> 1;                                   // 2 XCDs per batch
    const int row0 = (((bid >> 3) << 1) | (xcd & 1)) * 64;    // 64-row tile

    int goffA[4];
#pragma unroll
    for (int i = 0; i < 4; ++i) {
        int p = (w * 4 + i) * 64 + lane;
        int rA = p >> 5;
        goffA[i] = rA * 256 + (((p & 31) ^ (rA & 31)) << 3);
    }

    const unsigned short* gmc_b = gmc + (size_t)b * M_ * C_;
    const unsigned short* gcm3_b = gcm3 + (size_t)b * 524288;

    auto dmaA = [&](int tile, int reg) {
#pragma unroll
        for (int i = 0; i < 4; ++i)
            __builtin_amdgcn_global_load_lds(GLB_AS(gmc_b + (size_t)tile * 16384 + goffA[i]),
                                             LDS_AS(&sGmcD[reg * 16384 + (w * 4 + i) * 512]), 16, 0, 0);
    };
    auto dmaB = [&](int pair) {
#pragma unroll
        for (int i = 0; i < 8; ++i)
            __builtin_amdgcn_global_load_lds(GLB_AS(gcm3_b + (size_t)pair * 32768 + (w * 8 + i) * 512 + lane * 8),
                                             LDS_AS(&sGcm3[(w * 8 + i) * 512]), 16, 0, 0);
    };

    dmaA(0, 0);
    dmaA(1, 1);
    dmaB(0);

    // Q: my 32 rows, row norm, normalize -> bf16 B-frags
    short8 qf[2][8];
#pragma unroll
    for (int rt = 0; rt < 2; ++rt) {
        const float* lrow = l + ((size_t)b * N_ + row0 + rh * 32 + rt * 16 + l15) * C_;
        U16x8 qt[8];
        float ss = 0.f;
#pragma unroll
        for (int kk = 0; kk < 8; ++kk) {
            float4 x0 = *(const float4*)(lrow + kk * 32 + quad * 8);
            float4 x1 = *(const float4*)(lrow + kk * 32 + quad * 8 + 4);
            ss += x0.x*x0.x + x0.y*x0.y + x0.z*x0.z + x0.w*x0.w;
            ss += x1.x*x1.x + x1.y*x1.y + x1.z*x1.z + x1.w*x1.w;
            qt[kk].us[0] = f2bf(x0.x); qt[kk].us[1] = f2bf(x0.y);
            qt[kk].us[2] = f2bf(x0.z); qt[kk].us[3] = f2bf(x0.w);
            qt[kk].us[4] = f2bf(x1.x); qt[kk].us[5] = f2bf(x1.y);
            qt[kk].us[6] = f2bf(x1.z); qt[kk].us[7] = f2bf(x1.w);
        }
        ss += __shfl_xor(ss, 16);
        ss += __shfl_xor(ss, 32);
        const float invl = 1.0f / fmaxf(sqrtf(ss), 1e-8f);
#pragma unroll
        for (int kk = 0; kk < 8; ++kk) {
            U16x8 t;
#pragma unroll
            for (int j = 0; j < 8; ++j) t.us[j] = f2bf(bf2f(qt[kk].us[j]) * invl);
            qf[rt][kk] = t.s8;
        }
    }

    __syncthreads();   // drains pair-0 staging

    f32x4 zero = {0.f, 0.f, 0.f, 0.f};
    f32x4 o[2][16];
#pragma unroll
    for (int i = 0; i < 2; ++i)
#pragma unroll
        for (int j = 0; j < 16; ++j) o[i][j] = zero;
    float dl0 = 0.f, dl1 = 0.f;

    const unsigned short* gAbase = &sGmcD[(kh * 16 + l15) * 256];
    const int rxor = (kh * 16 + l15) & 31;
    const unsigned short* gB3 = &sGcm3[kh * 8192 + quad * 128 + l15 * 8];

    for (int p = 0; p < 16; ++p) {
        U16x4 pkE0, pkE1, pkO0, pkO1;

        {   // G1 even tile (region 0)
            f32x4 sa0 = zero, sa1 = zero;
#pragma unroll
            for (int kk = 0; kk < 8; ++kk) {
                short8 ag = *(const short8*)&gAbase[((kk * 4 + quad) ^ rxor) << 3];
                sa0 = __builtin_amdgcn_mfma_f32_16x16x32_bf16(ag, qf[0][kk], sa0, 0, 0, 0);
                sa1 = __builtin_amdgcn_mfma_f32_16x16x32_bf16(ag, qf[1][kk], sa1, 0, 0, 0);
            }
#pragma unroll
            for (int r = 0; r < 4; ++r) {
                float p0 = exp2f(sa0[r] * 3.6067376022224085f);
                float p1 = exp2f(sa1[r] * 3.6067376022224085f);
                dl0 += p0; dl1 += p1;
                pkE0.us[r] = f2bf(p0);
                pkE1.us[r] = f2bf(p1);
            }
        }
        {   // G1 odd tile (region 1)
            f32x4 sa0 = zero, sa1 = zero;
#pragma unroll
            for (int kk = 0; kk < 8; ++kk) {
                short8 ag = *(const short8*)&gAbase[16384 + (((kk * 4 + quad) ^ rxor) << 3)];
                sa0 = __builtin_amdgcn_mfma_f32_16x16x32_bf16(ag, qf[0][kk], sa0, 0, 0, 0);
                sa1 = __builtin_amdgcn_mfma_f32_16x16x32_bf16(ag, qf[1][kk], sa1, 0, 0, 0);
            }
#pragma unroll
            for (int r = 0; r < 4; ++r) {
                float p0 = exp2f(sa0[r] * 3.6067376022224085f);
                float p1 = exp2f(sa1[r] * 3.6067376022224085f);
                dl0 += p0; dl1 += p1;
                pkO0.us[r] = f2bf(p0);
                pkO1.us[r] = f2bf(p1);
            }
        }

        __syncthreads();                    // barrier A
        if (p < 15) { dmaA(2 * p + 2, 0); dmaA(2 * p + 3, 1); }

        // G2 with K=32: A = {pkE, pkO} packed (k = quad*8+j)
        U16x8 ap0, ap1;
#pragma unroll
        for (int r = 0; r < 4; ++r) {
            ap0.us[r] = pkE0.us[r]; ap0.us[4 + r] = pkO0.us[r];
            ap1.us[r] = pkE1.us[r]; ap1.us[4 + r] = pkO1.us[r];
        }
#pragma unroll
        for (int ct = 0; ct < 16; ++ct) {
            U16x8 bb;
            bb.u4 = *(const uint4*)&gB3[ct * 512];
            o[0][ct] = __builtin_amdgcn_mfma_f32_16x16x32_bf16(ap0.s8, bb.s8, o[0][ct], 0, 0, 0);
            o[1][ct] = __builtin_amdgcn_mfma_f32_16x16x32_bf16(ap1.s8, bb.s8, o[1][ct], 0, 0, 0);
        }

        __syncthreads();                    // barrier B
        if (p < 15) dmaB(p + 1);
    }

    // denominators: quad-reduce, publish per key-quarter per row
    {
        float d0 = dl0;
        d0 += __shfl_xor(d0, 16);
        d0 += __shfl_xor(d0, 32);
        float d1 = dl1;
        d1 += __shfl_xor(d1, 16);
        d1 += __shfl_xor(d1, 32);
        if (quad == 0) {
            sDen[kh][rh * 32 + l15] = d0;
            sDen[kh][rh * 32 + 16 + l15] = d1;
        }
    }

    // O reduction: 4 static rounds (rh x rt) through 64 KB LDS dump
    f32x4* red4 = (f32x4*)sMem;
    const int wslot = kh * 1024 + quad * 16 + l15;
    const int rslot = (4 * kh) * 64 + quad * 16 + l15;
    f32x4 oacc0[4], oacc1[4];

#define RED_ROUND(RH, OSRC, ODST)                                              \
    __syncthreads();                                                           \
    if (rh == (RH)) {                                                          \
        _Pragma("unroll")                                                      \
        for (int j = 0; j < 16; ++j) red4[wslot + j * 64] = OSRC[j];           \
    }                                                                          \
    __syncthreads();                                                           \
    if (rh == (RH)) {                                                          \
        _Pragma("unroll")                                                      \
        for (int jj = 0; jj < 4; ++jj) {                                       \
            const int base = rslot + jj * 64;                                  \
            ODST[jj] = red4[base] + red4[base + 1024] +                        \
                       red4[base + 2048] + red4[base + 3072];                  \
        }                                                                      \
    }

    RED_ROUND(0, o[0], oacc0)
    RED_ROUND(0, o[1], oacc1)
    RED_ROUND(1, o[0], oacc0)
    RED_ROUND(1, o[1], oacc1)
#undef RED_ROUND

    // epilogue: wave (kh, rh) owns rows [32rh,32rh+32), c [64kh, 64kh+64)
    const float* lb = l + ((size_t)b * N_ + row0 + rh * 32) * C_;
    float* ob = out + ((size_t)b * N_ + row0 + rh * 32) * C_;
#pragma unroll
    for (int r = 0; r < 4; ++r) {
        {   // row-tile 0
            const int row = quad * 4 + r;
            const int grow = rh * 32 + row;
            const float inv = 1.f / (sDen[0][grow] + sDen[1][grow] + sDen[2][grow] + sDen[3][grow]);
            const size_t rb = (size_t)row * C_;
#pragma unroll
            for (int jj = 0; jj < 4; ++jj) {
                const int c = kh * 64 + jj * 16 + l15;
                ob[rb + c] = lb[rb + c] + oacc0[jj][r] * inv;
            }
        }
        {   // row-tile 1
            const int row = 16 + quad * 4 + r;
            const int grow = rh * 32 + row;
            const float inv = 1.f / (sDen[0][grow] + sDen[1][grow] + sDen[2][grow] + sDen[3][grow]);
            const size_t rb = (size_t)row * C_;
#pragma unroll
            for (int jj = 0; jj < 4; ++jj) {
                const int c = kh * 64 + jj * 16 + l15;
                ob[rb + c] = lb[rb + c] + oacc1[jj][r] * inv;
            }
        }
    }
}

extern "C" void kernel_launch(void* const* d_in, const int* in_sizes, int n_in,
                              void* d_out, int out_size, void* d_ws, size_t ws_size,
                              hipStream_t stream) {
    (void)in_sizes; (void)n_in; (void)out_size; (void)ws_size;
    const float* l = (const float*)d_in[0];
    const float* g = (const float*)d_in[1];
    float* outp = (float*)d_out;

    char* ws = (char*)d_ws;
    unsigned short* gmc = (unsigned short*)ws;                                   // 4 MB ([b][m][c] normalized)
    unsigned short* gcm3 = (unsigned short*)(ws + (size_t)B_ * M_ * C_ * 2);     // 4 MB (pair-frag raw)

    void* args[] = {(void*)&l, (void*)&g, (void*)&gcm3, (void*)&gmc, (void*)&outp};
    hipLaunchCooperativeKernel((const void*)k_fused, dim3(256), dim3(512),
                               args, 0, stream);
}